// Round 4
// baseline (134.887 us; speedup 1.0000x reference)
//
#include <hip/hip_runtime.h>

#define NN 8192
#define DD 128
#define CH 16           // column chunks
#define CPC (NN / CH)   // cols per chunk = 512
#define TILES (CPC / 64)
#define NPART 64        // partial-sum bins

typedef __bf16 bf16x8 __attribute__((ext_vector_type(8)));
typedef float f32x4 __attribute__((ext_vector_type(4)));

// Max-network init: most negative finite float (all scores are < 0 by the -70 bias).
#define PACK_INIT __uint_as_float(0xFF7FFFFFu)

// Pack (score, idx): high 19 bits of fp32 score, idx in low 13. Scores are
// always NEGATIVE (score = dot - 0.5*sq_col - 70), so under fmaxf a larger idx
// makes the float more negative -> ties prefer the SMALLER idx (matches top_k).
static __device__ __forceinline__ float packsi(float s, unsigned idx) {
  return __uint_as_float((__float_as_uint(s) & 0xFFFFE000u) | idx);
}

// Sorted-insert (DESCENDING list, keep top-k LARGEST) via med3:
// q0' = max(q0, v); qk' = med3(v, q[k-1], qk). Depth 1, full-rate VOP3.
#define NET4(S0, S1, S2, S3, v)                                                \
  {                                                                            \
    float v_ = (v), o0 = S0, o1 = S1, o2 = S2;                                 \
    S0 = fmaxf(o0, v_);                                                        \
    S1 = __builtin_amdgcn_fmed3f(v_, o0, o1);                                  \
    S2 = __builtin_amdgcn_fmed3f(v_, o1, o2);                                  \
    S3 = __builtin_amdgcn_fmed3f(v_, o2, S3);                                  \
  }
#define NET5(S0, S1, S2, S3, S4, v)                                            \
  {                                                                            \
    float v_ = (v), o0 = S0, o1 = S1, o2 = S2, o3 = S3;                        \
    S0 = fmaxf(o0, v_);                                                        \
    S1 = __builtin_amdgcn_fmed3f(v_, o0, o1);                                  \
    S2 = __builtin_amdgcn_fmed3f(v_, o1, o2);                                  \
    S3 = __builtin_amdgcn_fmed3f(v_, o2, o3);                                  \
    S4 = __builtin_amdgcn_fmed3f(v_, o3, S4);                                  \
  }

static __device__ __forceinline__ unsigned short f2bf(float f) {
  unsigned u = __float_as_uint(f);
  u += 0x7FFFu + ((u >> 16) & 1u);   // round-to-nearest-even
  return (unsigned short)(u >> 16);
}

// width-16 global->LDS DMA (linear LDS dest = wave-uniform base + lane*16).
static __device__ __forceinline__ void gload_lds16(const void* g, void* l) {
  __builtin_amdgcn_global_load_lds(
      (const __attribute__((address_space(1))) unsigned*)g,
      (__attribute__((address_space(3))) unsigned*)l, 16, 0, 0);
}

// Kernel 1: f32->bf16 convert, staged col-score bias (-0.5*sq - 70), zero
// bins + completion counter.
__global__ __launch_bounds__(256) void prep_kernel(const float* __restrict__ x,
                                                   unsigned short* __restrict__ xb,
                                                   float* __restrict__ sq,
                                                   float* __restrict__ partial) {
  const int wave = threadIdx.x >> 6, lane = threadIdx.x & 63;
  const int row = blockIdx.x * 4 + wave;
  const float2 v = ((const float2*)(x + (size_t)row * DD))[lane];
  float ss = v.x * v.x + v.y * v.y;
#pragma unroll
  for (int off = 32; off; off >>= 1) ss += __shfl_down(ss, off);
  if (lane == 0) sq[row] = fmaf(-0.5f, ss, -70.0f);   // C-init for MFMA epilogue
  unsigned packed = (unsigned)f2bf(v.x) | ((unsigned)f2bf(v.y) << 16);
  ((unsigned*)(xb + (size_t)row * DD))[lane] = packed;
  if (blockIdx.x == 0 && threadIdx.x < NPART + 1) partial[threadIdx.x] = 0.0f;
}

// Kernel 2 (R2-measured-best config): bf16-MFMA scores (C preloaded with
// -0.5*sq_col-70) + med3 packed top-k. 64 rows/wave (4 row-groups), block =
// 256 rows x 512 cols, grid (32,16) = 512 blocks = 2/CU. Occupancy lesson
// (R3): 4 waves/SIMD needs VGPR<=128 -> 32 rows/wave -> 2x LDS/DMA traffic
// per score -> net loss; 3/SIMD impossible (VGPR steps {64,128,256}). Keep 2.
__global__ __launch_bounds__(256, 2) void dist_topk_kernel(
    const unsigned short* __restrict__ xb, const float* __restrict__ sq,
    float* __restrict__ pscore) {
  const int t = threadIdx.x;
  const int wave = t >> 6, lane = t & 63;
  const int lrow = lane & 15, lquad = lane >> 4;
  const int rowBase = blockIdx.x * 256;
  const int chunk = blockIdx.y;
  const int j0 = chunk * CPC;
  const bool hasDiag = ((blockIdx.x >> 1) == (int)blockIdx.y);

  __shared__ unsigned short colsB[2][64 * DD];   // 2 x 16 KB, XOR-swizzled image
  __shared__ float sqs_all[CPC];                 // whole chunk's col bias, 2 KB

  // A fragments for 4 row-groups: lane holds X[row][k=lquad*8+j].
  const int r0 = rowBase + wave * 64 + lrow;     // group g row = r0 + g*16
  const unsigned short* ap0 = xb + (size_t)(r0)*DD + lquad * 8;
  const unsigned short* ap1 = xb + (size_t)(r0 + 16) * DD + lquad * 8;
  const unsigned short* ap2 = xb + (size_t)(r0 + 32) * DD + lquad * 8;
  const unsigned short* ap3 = xb + (size_t)(r0 + 48) * DD + lquad * 8;
  bf16x8 a00 = *(const bf16x8*)(ap0), a01 = *(const bf16x8*)(ap0 + 32),
         a02 = *(const bf16x8*)(ap0 + 64), a03 = *(const bf16x8*)(ap0 + 96);
  bf16x8 a10 = *(const bf16x8*)(ap1), a11 = *(const bf16x8*)(ap1 + 32),
         a12 = *(const bf16x8*)(ap1 + 64), a13 = *(const bf16x8*)(ap1 + 96);
  bf16x8 a20 = *(const bf16x8*)(ap2), a21 = *(const bf16x8*)(ap2 + 32),
         a22 = *(const bf16x8*)(ap2 + 64), a23 = *(const bf16x8*)(ap2 + 96);
  bf16x8 a30 = *(const bf16x8*)(ap3), a31 = *(const bf16x8*)(ap3 + 32),
         a32 = *(const bf16x8*)(ap3 + 64), a33 = *(const bf16x8*)(ap3 + 96);

  // Packed sorted lists (descending), one per row-group.
  float q00 = PACK_INIT, q01 = PACK_INIT, q02 = PACK_INIT, q03 = PACK_INIT,
        q04 = PACK_INIT;
  float q10 = PACK_INIT, q11 = PACK_INIT, q12 = PACK_INIT, q13 = PACK_INIT,
        q14 = PACK_INIT;
  float q20 = PACK_INIT, q21 = PACK_INIT, q22 = PACK_INIT, q23 = PACK_INIT,
        q24 = PACK_INIT;
  float q30 = PACK_INIT, q31 = PACK_INIT, q32 = PACK_INIT, q33 = PACK_INIT,
        q34 = PACK_INIT;

  // DMA source pre-swizzle: LDS[i] = src[p(i)] with the involution
  // p(i) = (i & ~15) | ((i&15) ^ ((i>>4)&15)); identical image to the old
  // reg-staged LDS[p(t)] = src[t] store (p is an involution, p(i+256k)=p(i)+256k).
  const int psl = (t & ~15) | ((t ^ (t >> 4)) & 15);

#define ISSUE_TILE(buf, jtrow)                                                 \
  {                                                                            \
    const float4* s_ = (const float4*)(xb + (size_t)(jtrow)*DD);               \
    char* l_ = (char*)(&colsB[buf][0]) + wave * 1024;                          \
    gload_lds16(s_ + psl, l_);                                                 \
    gload_lds16(s_ + psl + 256, l_ + 4096);                                    \
    gload_lds16(s_ + psl + 512, l_ + 8192);                                    \
    gload_lds16(s_ + psl + 768, l_ + 12288);                                   \
  }

  // Prologue: stage whole-chunk col bias + DMA tile 0.
  sqs_all[t] = sq[j0 + t];
  sqs_all[t + 256] = sq[j0 + 256 + t];
  ISSUE_TILE(0, j0)

#define KBODY(INSROW)                                                          \
  for (int it = 0; it < TILES; ++it) {                                         \
    const int jt = j0 + it * 64;                                               \
    const int cur = it & 1;                                                    \
    __syncthreads(); /* drains this tile's DMA (vmcnt) + LDS writes */         \
    if (it + 1 < TILES) { ISSUE_TILE(cur ^ 1, jt + 64) }                       \
    _Pragma("unroll")                                                          \
    for (int ct = 0; ct < 4; ++ct) {                                           \
      const unsigned short* bb = &colsB[cur][(ct * 16 + lrow) * DD];           \
      bf16x8 b0 = *(const bf16x8*)(bb + (((0 + lquad) ^ lrow) << 3));          \
      bf16x8 b1 = *(const bf16x8*)(bb + (((4 + lquad) ^ lrow) << 3));          \
      bf16x8 b2 = *(const bf16x8*)(bb + (((8 + lquad) ^ lrow) << 3));          \
      bf16x8 b3 = *(const bf16x8*)(bb + (((12 + lquad) ^ lrow) << 3));         \
      const f32x4 nsq4 = *(const f32x4*)&sqs_all[it * 64 + ct * 16 + lquad * 4];\
      f32x4 ac0 = __builtin_amdgcn_mfma_f32_16x16x32_bf16(b0, a00, nsq4, 0, 0, 0);\
      f32x4 ac1 = __builtin_amdgcn_mfma_f32_16x16x32_bf16(b0, a10, nsq4, 0, 0, 0);\
      f32x4 ac2 = __builtin_amdgcn_mfma_f32_16x16x32_bf16(b0, a20, nsq4, 0, 0, 0);\
      f32x4 ac3 = __builtin_amdgcn_mfma_f32_16x16x32_bf16(b0, a30, nsq4, 0, 0, 0);\
      ac0 = __builtin_amdgcn_mfma_f32_16x16x32_bf16(b1, a01, ac0, 0, 0, 0);    \
      ac1 = __builtin_amdgcn_mfma_f32_16x16x32_bf16(b1, a11, ac1, 0, 0, 0);    \
      ac2 = __builtin_amdgcn_mfma_f32_16x16x32_bf16(b1, a21, ac2, 0, 0, 0);    \
      ac3 = __builtin_amdgcn_mfma_f32_16x16x32_bf16(b1, a31, ac3, 0, 0, 0);    \
      ac0 = __builtin_amdgcn_mfma_f32_16x16x32_bf16(b2, a02, ac0, 0, 0, 0);    \
      ac1 = __builtin_amdgcn_mfma_f32_16x16x32_bf16(b2, a12, ac1, 0, 0, 0);    \
      ac2 = __builtin_amdgcn_mfma_f32_16x16x32_bf16(b2, a22, ac2, 0, 0, 0);    \
      ac3 = __builtin_amdgcn_mfma_f32_16x16x32_bf16(b2, a32, ac3, 0, 0, 0);    \
      ac0 = __builtin_amdgcn_mfma_f32_16x16x32_bf16(b3, a03, ac0, 0, 0, 0);    \
      ac1 = __builtin_amdgcn_mfma_f32_16x16x32_bf16(b3, a13, ac1, 0, 0, 0);    \
      ac2 = __builtin_amdgcn_mfma_f32_16x16x32_bf16(b3, a23, ac2, 0, 0, 0);    \
      ac3 = __builtin_amdgcn_mfma_f32_16x16x32_bf16(b3, a33, ac3, 0, 0, 0);    \
      const unsigned colb = (unsigned)(jt + ct * 16 + lquad * 4);              \
      _Pragma("unroll")                                                        \
      for (int r = 0; r < 4; ++r) {                                            \
        const unsigned cr = colb + r;                                          \
        INSROW(0, packsi(ac0[r], cr));                                         \
        INSROW(1, packsi(ac1[r], cr));                                         \
        INSROW(2, packsi(ac2[r], cr));                                         \
        INSROW(3, packsi(ac3[r], cr));                                         \
      }                                                                        \
    }                                                                          \
  }

#define INS4(G, V) NET4(q##G##0, q##G##1, q##G##2, q##G##3, (V))
#define INS5(G, V) NET5(q##G##0, q##G##1, q##G##2, q##G##3, q##G##4, (V))

  if (hasDiag) {
    KBODY(INS5)
  } else {
    KBODY(INS4)
  }
#undef KBODY

  // Merge across lquads (lanes sharing lrow hold the same 4 rows).
#define MERGE4(G, M)                                                           \
  {                                                                            \
    float o0 = __shfl_xor(q##G##0, M), o1 = __shfl_xor(q##G##1, M),            \
          o2 = __shfl_xor(q##G##2, M), o3 = __shfl_xor(q##G##3, M);            \
    NET4(q##G##0, q##G##1, q##G##2, q##G##3, o0);                              \
    NET4(q##G##0, q##G##1, q##G##2, q##G##3, o1);                              \
    NET4(q##G##0, q##G##1, q##G##2, q##G##3, o2);                              \
    NET4(q##G##0, q##G##1, q##G##2, q##G##3, o3);                              \
  }
#define MERGE5(G, M)                                                           \
  {                                                                            \
    float o0 = __shfl_xor(q##G##0, M), o1 = __shfl_xor(q##G##1, M),            \
          o2 = __shfl_xor(q##G##2, M), o3 = __shfl_xor(q##G##3, M),            \
          o4 = __shfl_xor(q##G##4, M);                                         \
    NET5(q##G##0, q##G##1, q##G##2, q##G##3, q##G##4, o0);                     \
    NET5(q##G##0, q##G##1, q##G##2, q##G##3, q##G##4, o1);                     \
    NET5(q##G##0, q##G##1, q##G##2, q##G##3, q##G##4, o2);                     \
    NET5(q##G##0, q##G##1, q##G##2, q##G##3, q##G##4, o3);                     \
    NET5(q##G##0, q##G##1, q##G##2, q##G##3, q##G##4, o4);                     \
  }
  if (hasDiag) {
    MERGE5(0, 16) MERGE5(1, 16) MERGE5(2, 16) MERGE5(3, 16)
    MERGE5(0, 32) MERGE5(1, 32) MERGE5(2, 32) MERGE5(3, 32)
  } else {
    MERGE4(0, 16) MERGE4(1, 16) MERGE4(2, 16) MERGE4(3, 16)
    MERGE4(0, 32) MERGE4(1, 32) MERGE4(2, 32) MERGE4(3, 32)
  }

  if (lquad == 0) {
    // pscore layout: [row][CH*5] -> coalesced per-row read in final_kernel.
    float* b0p = pscore + (size_t)(r0)*80 + chunk * 5;
    b0p[0] = q00; b0p[1] = q01; b0p[2] = q02; b0p[3] = q03; b0p[4] = q04;
    float* b1p = pscore + (size_t)(r0 + 16) * 80 + chunk * 5;
    b1p[0] = q10; b1p[1] = q11; b1p[2] = q12; b1p[3] = q13; b1p[4] = q14;
    float* b2p = pscore + (size_t)(r0 + 32) * 80 + chunk * 5;
    b2p[0] = q20; b2p[1] = q21; b2p[2] = q22; b2p[3] = q23; b2p[4] = q24;
    float* b3p = pscore + (size_t)(r0 + 48) * 80 + chunk * 5;
    b3p[0] = q30; b3p[1] = q31; b3p[2] = q32; b3p[3] = q33; b3p[4] = q34;
  }
}

// Kernel 3: chunk merge (packed, max networks) -> neg idx -> exact fp32 hinge
// -> 64 bins; LAST finishing block (device-scope atomic counter) sums the bins
// with the exact same shfl-tree order the old reduce_kernel used -> absmax 0.0
// preserved, one dispatch + launch gap removed.
__global__ __launch_bounds__(256) void final_kernel(const float* __restrict__ x,
                                                    const float* __restrict__ pos,
                                                    const float* __restrict__ pscore,
                                                    float* __restrict__ partial,
                                                    float* __restrict__ out) {
  const int wave = threadIdx.x >> 6, lane = threadIdx.x & 63;
  const int row = blockIdx.x * 4 + wave;

  float q0 = PACK_INIT, q1 = PACK_INIT, q2 = PACK_INIT, q3 = PACK_INIT,
        q4 = PACK_INIT;
  if (lane < CH) {
    const float* b = pscore + (size_t)row * 80 + lane * 5;   // contiguous row
    q0 = b[0]; q1 = b[1]; q2 = b[2]; q3 = b[3]; q4 = b[4];
  }
#pragma unroll
  for (int m = 1; m < CH; m <<= 1) {
    float o0 = __shfl_xor(q0, m), o1 = __shfl_xor(q1, m), o2 = __shfl_xor(q2, m),
          o3 = __shfl_xor(q3, m), o4 = __shfl_xor(q4, m);
    NET5(q0, q1, q2, q3, q4, o0);
    NET5(q0, q1, q2, q3, q4, o1);
    NET5(q0, q1, q2, q3, q4, o2);
    NET5(q0, q1, q2, q3, q4, o3);
    NET5(q0, q1, q2, q3, q4, o4);
  }
  const int nidx = (int)(__float_as_uint(__shfl(q4, 0)) & 0x1FFFu);

  const float2 xv  = ((const float2*)(x   + (size_t)row  * DD))[lane];
  const float2 pv  = ((const float2*)(pos + (size_t)row  * DD))[lane];
  const float2 nvv = ((const float2*)(x   + (size_t)nidx * DD))[lane];
  float a0 = xv.x - pv.x + 1e-6f, a1 = xv.y - pv.y + 1e-6f;
  float b0 = xv.x - nvv.x + 1e-6f, b1 = xv.y - nvv.y + 1e-6f;
  float dap = a0 * a0 + a1 * a1;
  float dan = b0 * b0 + b1 * b1;
#pragma unroll
  for (int off = 32; off; off >>= 1) {
    dap += __shfl_down(dap, off);
    dan += __shfl_down(dan, off);
  }
  __shared__ float hs[4];
  if (lane == 0) hs[wave] = fmaxf(sqrtf(dap) - sqrtf(dan) + 0.3f, 0.0f);
  __syncthreads();

  if (wave == 0) {
    float old = 0.0f;
    if (lane == 0) {
      float s = hs[0] + hs[1] + hs[2] + hs[3];
      atomicAdd(&partial[blockIdx.x & (NPART - 1)], s);
      __threadfence();                       // bin add visible before counter
      old = atomicAdd(&partial[NPART], 1.0f);  // completion counter (exact fp)
    }
    old = __shfl(old, 0);
    if (old == (float)(NN / 4 - 1)) {
      // Last block: atomic-load bins (device-coherent), same shfl tree as the
      // old reduce_kernel (lane i holds bin i -> identical summation order).
      float v = atomicAdd(&partial[lane], 0.0f);
#pragma unroll
      for (int off = 32; off; off >>= 1) v += __shfl_down(v, off);
      if (lane == 0) out[0] = v * (1.0f / 8192.0f);
    }
  }
}

extern "C" void kernel_launch(void* const* d_in, const int* in_sizes, int n_in,
                              void* d_out, int out_size, void* d_ws, size_t ws_size,
                              hipStream_t stream) {
  const float* x   = (const float*)d_in[0];
  const float* pos = (const float*)d_in[1];
  float* out = (float*)d_out;

  char* w = (char*)d_ws;
  unsigned short* xb = (unsigned short*)w;                       // 2 MB
  float* sq = (float*)(w + (size_t)NN * DD * 2);                 // 32 KB
  float* pscore = (float*)(w + (size_t)NN * DD * 2 + (size_t)NN * 4);  // 2.62 MB
  float* partial = (float*)(w + (size_t)NN * DD * 2 + (size_t)NN * 4 +
                            (size_t)NN * 80 * 4);                // 260 B

  prep_kernel<<<NN / 4, 256, 0, stream>>>(x, xb, sq, partial);
  dist_topk_kernel<<<dim3(NN / 256, CH), 256, 0, stream>>>(xb, sq, pscore);
  final_kernel<<<NN / 4, 256, 0, stream>>>(x, pos, pscore, partial, out);
}

// Round 5
// 104.021 us; speedup vs baseline: 1.2967x; 1.2967x over previous
//
#include <hip/hip_runtime.h>

#define NN 8192
#define DD 128
#define CH 16           // column chunks
#define CPC (NN / CH)   // cols per chunk = 512
#define TILES (CPC / 64)
#define NPART 64        // partial-sum bins

typedef __bf16 bf16x8 __attribute__((ext_vector_type(8)));
typedef float f32x4 __attribute__((ext_vector_type(4)));

// Max-network init: most negative finite float (all scores are < 0 by the -70 bias).
#define PACK_INIT __uint_as_float(0xFF7FFFFFu)

// Pack (score, idx): high 19 bits of fp32 score, idx in low 13. Scores are
// always NEGATIVE (score = dot - 0.5*sq_col - 70), so under fmaxf a larger idx
// makes the float more negative -> ties prefer the SMALLER idx (matches top_k).
static __device__ __forceinline__ float packsi(float s, unsigned idx) {
  return __uint_as_float((__float_as_uint(s) & 0xFFFFE000u) | idx);
}

// Sorted-insert (DESCENDING list, keep top-k LARGEST) via med3:
// q0' = max(q0, v); qk' = med3(v, q[k-1], qk). Depth 1, full-rate VOP3.
#define NET4(S0, S1, S2, S3, v)                                                \
  {                                                                            \
    float v_ = (v), o0 = S0, o1 = S1, o2 = S2;                                 \
    S0 = fmaxf(o0, v_);                                                        \
    S1 = __builtin_amdgcn_fmed3f(v_, o0, o1);                                  \
    S2 = __builtin_amdgcn_fmed3f(v_, o1, o2);                                  \
    S3 = __builtin_amdgcn_fmed3f(v_, o2, S3);                                  \
  }
#define NET5(S0, S1, S2, S3, S4, v)                                            \
  {                                                                            \
    float v_ = (v), o0 = S0, o1 = S1, o2 = S2, o3 = S3;                        \
    S0 = fmaxf(o0, v_);                                                        \
    S1 = __builtin_amdgcn_fmed3f(v_, o0, o1);                                  \
    S2 = __builtin_amdgcn_fmed3f(v_, o1, o2);                                  \
    S3 = __builtin_amdgcn_fmed3f(v_, o2, o3);                                  \
    S4 = __builtin_amdgcn_fmed3f(v_, o3, S4);                                  \
  }

static __device__ __forceinline__ unsigned short f2bf(float f) {
  unsigned u = __float_as_uint(f);
  u += 0x7FFFu + ((u >> 16) & 1u);   // round-to-nearest-even
  return (unsigned short)(u >> 16);
}

// width-16 global->LDS DMA (linear LDS dest = wave-uniform base + lane*16).
static __device__ __forceinline__ void gload_lds16(const void* g, void* l) {
  __builtin_amdgcn_global_load_lds(
      (const __attribute__((address_space(1))) unsigned*)g,
      (__attribute__((address_space(3))) unsigned*)l, 16, 0, 0);
}

// Kernel 1: f32->bf16 convert, staged col-score bias (-0.5*sq - 70), zero bins.
__global__ __launch_bounds__(256) void prep_kernel(const float* __restrict__ x,
                                                   unsigned short* __restrict__ xb,
                                                   float* __restrict__ sq,
                                                   float* __restrict__ partial) {
  const int wave = threadIdx.x >> 6, lane = threadIdx.x & 63;
  const int row = blockIdx.x * 4 + wave;
  const float2 v = ((const float2*)(x + (size_t)row * DD))[lane];
  float ss = v.x * v.x + v.y * v.y;
#pragma unroll
  for (int off = 32; off; off >>= 1) ss += __shfl_down(ss, off);
  if (lane == 0) sq[row] = fmaf(-0.5f, ss, -70.0f);   // C-init for MFMA epilogue
  unsigned packed = (unsigned)f2bf(v.x) | ((unsigned)f2bf(v.y) << 16);
  ((unsigned*)(xb + (size_t)row * DD))[lane] = packed;
  if (blockIdx.x == 0 && threadIdx.x < NPART) partial[threadIdx.x] = 0.0f;
}

// Kernel 2 (R2-measured-best config): bf16-MFMA scores (C preloaded with
// -0.5*sq_col-70) + med3 packed top-k. 64 rows/wave (4 row-groups), block =
// 256 rows x 512 cols, grid (32,16) = 512 blocks = 2/CU. Occupancy lesson
// (R3): 4 waves/SIMD needs VGPR<=128 -> 32 rows/wave -> 2x LDS/DMA traffic
// per score -> net loss; 3/SIMD impossible (VGPR steps {64,128,256}). Keep 2.
// R4 lesson: no single-address completion counters / per-block device fences.
__global__ __launch_bounds__(256, 2) void dist_topk_kernel(
    const unsigned short* __restrict__ xb, const float* __restrict__ sq,
    float* __restrict__ pscore) {
  const int t = threadIdx.x;
  const int wave = t >> 6, lane = t & 63;
  const int lrow = lane & 15, lquad = lane >> 4;
  const int rowBase = blockIdx.x * 256;
  const int chunk = blockIdx.y;
  const int j0 = chunk * CPC;
  const bool hasDiag = ((blockIdx.x >> 1) == (int)blockIdx.y);

  __shared__ unsigned short colsB[2][64 * DD];   // 2 x 16 KB, XOR-swizzled image
  __shared__ float sqs_all[CPC];                 // whole chunk's col bias, 2 KB

  // A fragments for 4 row-groups: lane holds X[row][k=lquad*8+j].
  const int r0 = rowBase + wave * 64 + lrow;     // group g row = r0 + g*16
  const unsigned short* ap0 = xb + (size_t)(r0)*DD + lquad * 8;
  const unsigned short* ap1 = xb + (size_t)(r0 + 16) * DD + lquad * 8;
  const unsigned short* ap2 = xb + (size_t)(r0 + 32) * DD + lquad * 8;
  const unsigned short* ap3 = xb + (size_t)(r0 + 48) * DD + lquad * 8;
  bf16x8 a00 = *(const bf16x8*)(ap0), a01 = *(const bf16x8*)(ap0 + 32),
         a02 = *(const bf16x8*)(ap0 + 64), a03 = *(const bf16x8*)(ap0 + 96);
  bf16x8 a10 = *(const bf16x8*)(ap1), a11 = *(const bf16x8*)(ap1 + 32),
         a12 = *(const bf16x8*)(ap1 + 64), a13 = *(const bf16x8*)(ap1 + 96);
  bf16x8 a20 = *(const bf16x8*)(ap2), a21 = *(const bf16x8*)(ap2 + 32),
         a22 = *(const bf16x8*)(ap2 + 64), a23 = *(const bf16x8*)(ap2 + 96);
  bf16x8 a30 = *(const bf16x8*)(ap3), a31 = *(const bf16x8*)(ap3 + 32),
         a32 = *(const bf16x8*)(ap3 + 64), a33 = *(const bf16x8*)(ap3 + 96);

  // Packed sorted lists (descending), one per row-group.
  float q00 = PACK_INIT, q01 = PACK_INIT, q02 = PACK_INIT, q03 = PACK_INIT,
        q04 = PACK_INIT;
  float q10 = PACK_INIT, q11 = PACK_INIT, q12 = PACK_INIT, q13 = PACK_INIT,
        q14 = PACK_INIT;
  float q20 = PACK_INIT, q21 = PACK_INIT, q22 = PACK_INIT, q23 = PACK_INIT,
        q24 = PACK_INIT;
  float q30 = PACK_INIT, q31 = PACK_INIT, q32 = PACK_INIT, q33 = PACK_INIT,
        q34 = PACK_INIT;

  // DMA source pre-swizzle: LDS[i] = src[p(i)] with the involution
  // p(i) = (i & ~15) | ((i&15) ^ ((i>>4)&15)); identical image to the old
  // reg-staged LDS[p(t)] = src[t] store (p is an involution, p(i+256k)=p(i)+256k).
  const int psl = (t & ~15) | ((t ^ (t >> 4)) & 15);

#define ISSUE_TILE(buf, jtrow)                                                 \
  {                                                                            \
    const float4* s_ = (const float4*)(xb + (size_t)(jtrow)*DD);               \
    char* l_ = (char*)(&colsB[buf][0]) + wave * 1024;                          \
    gload_lds16(s_ + psl, l_);                                                 \
    gload_lds16(s_ + psl + 256, l_ + 4096);                                    \
    gload_lds16(s_ + psl + 512, l_ + 8192);                                    \
    gload_lds16(s_ + psl + 768, l_ + 12288);                                   \
  }

  // Prologue: stage whole-chunk col bias + DMA tile 0.
  sqs_all[t] = sq[j0 + t];
  sqs_all[t + 256] = sq[j0 + 256 + t];
  ISSUE_TILE(0, j0)

#define KBODY(INSROW)                                                          \
  for (int it = 0; it < TILES; ++it) {                                         \
    const int jt = j0 + it * 64;                                               \
    const int cur = it & 1;                                                    \
    __syncthreads(); /* drains this tile's DMA (vmcnt) + LDS writes */         \
    if (it + 1 < TILES) { ISSUE_TILE(cur ^ 1, jt + 64) }                       \
    _Pragma("unroll")                                                          \
    for (int ct = 0; ct < 4; ++ct) {                                           \
      const unsigned short* bb = &colsB[cur][(ct * 16 + lrow) * DD];           \
      bf16x8 b0 = *(const bf16x8*)(bb + (((0 + lquad) ^ lrow) << 3));          \
      bf16x8 b1 = *(const bf16x8*)(bb + (((4 + lquad) ^ lrow) << 3));          \
      bf16x8 b2 = *(const bf16x8*)(bb + (((8 + lquad) ^ lrow) << 3));          \
      bf16x8 b3 = *(const bf16x8*)(bb + (((12 + lquad) ^ lrow) << 3));         \
      const f32x4 nsq4 = *(const f32x4*)&sqs_all[it * 64 + ct * 16 + lquad * 4];\
      f32x4 ac0 = __builtin_amdgcn_mfma_f32_16x16x32_bf16(b0, a00, nsq4, 0, 0, 0);\
      f32x4 ac1 = __builtin_amdgcn_mfma_f32_16x16x32_bf16(b0, a10, nsq4, 0, 0, 0);\
      f32x4 ac2 = __builtin_amdgcn_mfma_f32_16x16x32_bf16(b0, a20, nsq4, 0, 0, 0);\
      f32x4 ac3 = __builtin_amdgcn_mfma_f32_16x16x32_bf16(b0, a30, nsq4, 0, 0, 0);\
      ac0 = __builtin_amdgcn_mfma_f32_16x16x32_bf16(b1, a01, ac0, 0, 0, 0);    \
      ac1 = __builtin_amdgcn_mfma_f32_16x16x32_bf16(b1, a11, ac1, 0, 0, 0);    \
      ac2 = __builtin_amdgcn_mfma_f32_16x16x32_bf16(b1, a21, ac2, 0, 0, 0);    \
      ac3 = __builtin_amdgcn_mfma_f32_16x16x32_bf16(b1, a31, ac3, 0, 0, 0);    \
      ac0 = __builtin_amdgcn_mfma_f32_16x16x32_bf16(b2, a02, ac0, 0, 0, 0);    \
      ac1 = __builtin_amdgcn_mfma_f32_16x16x32_bf16(b2, a12, ac1, 0, 0, 0);    \
      ac2 = __builtin_amdgcn_mfma_f32_16x16x32_bf16(b2, a22, ac2, 0, 0, 0);    \
      ac3 = __builtin_amdgcn_mfma_f32_16x16x32_bf16(b2, a32, ac3, 0, 0, 0);    \
      ac0 = __builtin_amdgcn_mfma_f32_16x16x32_bf16(b3, a03, ac0, 0, 0, 0);    \
      ac1 = __builtin_amdgcn_mfma_f32_16x16x32_bf16(b3, a13, ac1, 0, 0, 0);    \
      ac2 = __builtin_amdgcn_mfma_f32_16x16x32_bf16(b3, a23, ac2, 0, 0, 0);    \
      ac3 = __builtin_amdgcn_mfma_f32_16x16x32_bf16(b3, a33, ac3, 0, 0, 0);    \
      const unsigned colb = (unsigned)(jt + ct * 16 + lquad * 4);              \
      _Pragma("unroll")                                                        \
      for (int r = 0; r < 4; ++r) {                                            \
        const unsigned cr = colb + r;                                          \
        INSROW(0, packsi(ac0[r], cr));                                         \
        INSROW(1, packsi(ac1[r], cr));                                         \
        INSROW(2, packsi(ac2[r], cr));                                         \
        INSROW(3, packsi(ac3[r], cr));                                         \
      }                                                                        \
    }                                                                          \
  }

#define INS4(G, V) NET4(q##G##0, q##G##1, q##G##2, q##G##3, (V))
#define INS5(G, V) NET5(q##G##0, q##G##1, q##G##2, q##G##3, q##G##4, (V))

  if (hasDiag) {
    KBODY(INS5)
  } else {
    KBODY(INS4)
  }
#undef KBODY

  // Merge across lquads (lanes sharing lrow hold the same 4 rows).
#define MERGE4(G, M)                                                           \
  {                                                                            \
    float o0 = __shfl_xor(q##G##0, M), o1 = __shfl_xor(q##G##1, M),            \
          o2 = __shfl_xor(q##G##2, M), o3 = __shfl_xor(q##G##3, M);            \
    NET4(q##G##0, q##G##1, q##G##2, q##G##3, o0);                              \
    NET4(q##G##0, q##G##1, q##G##2, q##G##3, o1);                              \
    NET4(q##G##0, q##G##1, q##G##2, q##G##3, o2);                              \
    NET4(q##G##0, q##G##1, q##G##2, q##G##3, o3);                              \
  }
#define MERGE5(G, M)                                                           \
  {                                                                            \
    float o0 = __shfl_xor(q##G##0, M), o1 = __shfl_xor(q##G##1, M),            \
          o2 = __shfl_xor(q##G##2, M), o3 = __shfl_xor(q##G##3, M),            \
          o4 = __shfl_xor(q##G##4, M);                                         \
    NET5(q##G##0, q##G##1, q##G##2, q##G##3, q##G##4, o0);                     \
    NET5(q##G##0, q##G##1, q##G##2, q##G##3, q##G##4, o1);                     \
    NET5(q##G##0, q##G##1, q##G##2, q##G##3, q##G##4, o2);                     \
    NET5(q##G##0, q##G##1, q##G##2, q##G##3, q##G##4, o3);                     \
    NET5(q##G##0, q##G##1, q##G##2, q##G##3, q##G##4, o4);                     \
  }
  if (hasDiag) {
    MERGE5(0, 16) MERGE5(1, 16) MERGE5(2, 16) MERGE5(3, 16)
    MERGE5(0, 32) MERGE5(1, 32) MERGE5(2, 32) MERGE5(3, 32)
  } else {
    MERGE4(0, 16) MERGE4(1, 16) MERGE4(2, 16) MERGE4(3, 16)
    MERGE4(0, 32) MERGE4(1, 32) MERGE4(2, 32) MERGE4(3, 32)
  }

  if (lquad == 0) {
    // pscore layout: [row][CH*5] -> coalesced per-row read in final_kernel.
    float* b0p = pscore + (size_t)(r0)*80 + chunk * 5;
    b0p[0] = q00; b0p[1] = q01; b0p[2] = q02; b0p[3] = q03; b0p[4] = q04;
    float* b1p = pscore + (size_t)(r0 + 16) * 80 + chunk * 5;
    b1p[0] = q10; b1p[1] = q11; b1p[2] = q12; b1p[3] = q13; b1p[4] = q14;
    float* b2p = pscore + (size_t)(r0 + 32) * 80 + chunk * 5;
    b2p[0] = q20; b2p[1] = q21; b2p[2] = q22; b2p[3] = q23; b2p[4] = q24;
    float* b3p = pscore + (size_t)(r0 + 48) * 80 + chunk * 5;
    b3p[0] = q30; b3p[1] = q31; b3p[2] = q32; b3p[3] = q33; b3p[4] = q34;
  }
}

// Kernel 3: chunk merge (packed, max networks) -> neg idx -> exact fp32 hinge
// -> 64 bins. x[row]/pos[row] loads hoisted ABOVE the merge so their L2/L3
// latency overlaps the ~100-op merge chain (they're independent of it); only
// the x[nidx] gather is merge-dependent.
__global__ __launch_bounds__(256) void final_kernel(const float* __restrict__ x,
                                                    const float* __restrict__ pos,
                                                    const float* __restrict__ pscore,
                                                    float* __restrict__ partial) {
  const int wave = threadIdx.x >> 6, lane = threadIdx.x & 63;
  const int row = blockIdx.x * 4 + wave;

  // Independent loads first: overlap with merge below.
  const float2 xv  = ((const float2*)(x   + (size_t)row  * DD))[lane];
  const float2 pv  = ((const float2*)(pos + (size_t)row  * DD))[lane];

  float q0 = PACK_INIT, q1 = PACK_INIT, q2 = PACK_INIT, q3 = PACK_INIT,
        q4 = PACK_INIT;
  if (lane < CH) {
    const float* b = pscore + (size_t)row * 80 + lane * 5;   // contiguous row
    q0 = b[0]; q1 = b[1]; q2 = b[2]; q3 = b[3]; q4 = b[4];
  }
#pragma unroll
  for (int m = 1; m < CH; m <<= 1) {
    float o0 = __shfl_xor(q0, m), o1 = __shfl_xor(q1, m), o2 = __shfl_xor(q2, m),
          o3 = __shfl_xor(q3, m), o4 = __shfl_xor(q4, m);
    NET5(q0, q1, q2, q3, q4, o0);
    NET5(q0, q1, q2, q3, q4, o1);
    NET5(q0, q1, q2, q3, q4, o2);
    NET5(q0, q1, q2, q3, q4, o3);
    NET5(q0, q1, q2, q3, q4, o4);
  }
  const int nidx = (int)(__float_as_uint(__shfl(q4, 0)) & 0x1FFFu);

  const float2 nvv = ((const float2*)(x + (size_t)nidx * DD))[lane];
  float a0 = xv.x - pv.x + 1e-6f, a1 = xv.y - pv.y + 1e-6f;
  float b0 = xv.x - nvv.x + 1e-6f, b1 = xv.y - nvv.y + 1e-6f;
  float dap = a0 * a0 + a1 * a1;
  float dan = b0 * b0 + b1 * b1;
#pragma unroll
  for (int off = 32; off; off >>= 1) {
    dap += __shfl_down(dap, off);
    dan += __shfl_down(dan, off);
  }
  __shared__ float hs[4];
  if (lane == 0) hs[wave] = fmaxf(sqrtf(dap) - sqrtf(dan) + 0.3f, 0.0f);
  __syncthreads();
  if (threadIdx.x == 0) {
    float s = hs[0] + hs[1] + hs[2] + hs[3];
    atomicAdd(&partial[blockIdx.x & (NPART - 1)], s);
  }
}

// Kernel 4: one wave sums the 64 bins -> mean.
__global__ __launch_bounds__(64) void reduce_kernel(const float* __restrict__ partial,
                                                    float* __restrict__ out) {
  float v = partial[threadIdx.x];
#pragma unroll
  for (int off = 32; off; off >>= 1) v += __shfl_down(v, off);
  if (threadIdx.x == 0) out[0] = v * (1.0f / 8192.0f);
}

extern "C" void kernel_launch(void* const* d_in, const int* in_sizes, int n_in,
                              void* d_out, int out_size, void* d_ws, size_t ws_size,
                              hipStream_t stream) {
  const float* x   = (const float*)d_in[0];
  const float* pos = (const float*)d_in[1];
  float* out = (float*)d_out;

  char* w = (char*)d_ws;
  unsigned short* xb = (unsigned short*)w;                       // 2 MB
  float* sq = (float*)(w + (size_t)NN * DD * 2);                 // 32 KB
  float* pscore = (float*)(w + (size_t)NN * DD * 2 + (size_t)NN * 4);  // 2.62 MB
  float* partial = (float*)(w + (size_t)NN * DD * 2 + (size_t)NN * 4 +
                            (size_t)NN * 80 * 4);                // 256 B

  prep_kernel<<<NN / 4, 256, 0, stream>>>(x, xb, sq, partial);
  dist_topk_kernel<<<dim3(NN / 256, CH), 256, 0, stream>>>(xb, sq, pscore);
  final_kernel<<<NN / 4, 256, 0, stream>>>(x, pos, pscore, partial);
  reduce_kernel<<<1, 64, 0, stream>>>(partial, out);
}

// Round 6
// 103.886 us; speedup vs baseline: 1.2984x; 1.0013x over previous
//
#include <hip/hip_runtime.h>

#define NN 8192
#define DD 128
#define CH 16           // column chunks
#define CPC (NN / CH)   // cols per chunk = 512
#define TILES (CPC / 64)
#define NPART 64        // partial-sum bins

typedef __bf16 bf16x8 __attribute__((ext_vector_type(8)));
typedef float f32x4 __attribute__((ext_vector_type(4)));

// Max-network init: most negative finite float (all scores are < 0 by the -70 bias).
#define PACK_INIT __uint_as_float(0xFF7FFFFFu)

// Pack (score, idx): high 19 bits of fp32 score, idx in low 13. Scores are
// always NEGATIVE (score = dot - 0.5*sq_col - 70), so under fmaxf a larger idx
// makes the float more negative -> ties prefer the SMALLER idx (matches top_k).
static __device__ __forceinline__ float packsi(float s, unsigned idx) {
  return __uint_as_float((__float_as_uint(s) & 0xFFFFE000u) | idx);
}

// Sorted-insert (DESCENDING list, keep top-k LARGEST) via med3:
// q0' = max(q0, v); qk' = med3(v, q[k-1], qk). Depth 1, full-rate VOP3.
#define NET4(S0, S1, S2, S3, v)                                                \
  {                                                                            \
    float v_ = (v), o0 = S0, o1 = S1, o2 = S2;                                 \
    S0 = fmaxf(o0, v_);                                                        \
    S1 = __builtin_amdgcn_fmed3f(v_, o0, o1);                                  \
    S2 = __builtin_amdgcn_fmed3f(v_, o1, o2);                                  \
    S3 = __builtin_amdgcn_fmed3f(v_, o2, S3);                                  \
  }
#define NET5(S0, S1, S2, S3, S4, v)                                            \
  {                                                                            \
    float v_ = (v), o0 = S0, o1 = S1, o2 = S2, o3 = S3;                        \
    S0 = fmaxf(o0, v_);                                                        \
    S1 = __builtin_amdgcn_fmed3f(v_, o0, o1);                                  \
    S2 = __builtin_amdgcn_fmed3f(v_, o1, o2);                                  \
    S3 = __builtin_amdgcn_fmed3f(v_, o2, o3);                                  \
    S4 = __builtin_amdgcn_fmed3f(v_, o3, S4);                                  \
  }

static __device__ __forceinline__ unsigned short f2bf(float f) {
  unsigned u = __float_as_uint(f);
  u += 0x7FFFu + ((u >> 16) & 1u);   // round-to-nearest-even
  return (unsigned short)(u >> 16);
}

// width-16 global->LDS DMA (linear LDS dest = wave-uniform base + lane*16).
static __device__ __forceinline__ void gload_lds16(const void* g, void* l) {
  __builtin_amdgcn_global_load_lds(
      (const __attribute__((address_space(1))) unsigned*)g,
      (__attribute__((address_space(3))) unsigned*)l, 16, 0, 0);
}

// Kernel 1: f32->bf16 convert, staged col-score bias (-0.5*sq - 70), zero bins.
__global__ __launch_bounds__(256) void prep_kernel(const float* __restrict__ x,
                                                   unsigned short* __restrict__ xb,
                                                   float* __restrict__ sq,
                                                   float* __restrict__ partial) {
  const int wave = threadIdx.x >> 6, lane = threadIdx.x & 63;
  const int row = blockIdx.x * 4 + wave;
  const float2 v = ((const float2*)(x + (size_t)row * DD))[lane];
  float ss = v.x * v.x + v.y * v.y;
#pragma unroll
  for (int off = 32; off; off >>= 1) ss += __shfl_down(ss, off);
  if (lane == 0) sq[row] = fmaf(-0.5f, ss, -70.0f);   // C-init for MFMA epilogue
  unsigned packed = (unsigned)f2bf(v.x) | ((unsigned)f2bf(v.y) << 16);
  ((unsigned*)(xb + (size_t)row * DD))[lane] = packed;
  if (blockIdx.x == 0 && threadIdx.x < NPART) partial[threadIdx.x] = 0.0f;
}

// Kernel 2: bf16-MFMA scores + med3 packed top-k, R2 config (64 rows/wave,
// 256x512 block, grid (32,16), 2 blocks/CU). THIS ROUND: 2-stage software
// pipeline across ct (READS(ct+1); MFMA(ct+1); INSERTS(ct)) with dual
// b-frag/acc register sets, so each MFMA cluster's ~200cy chain latency is
// covered by the PREVIOUS ct's insert VALU stream, and ds_read latency by
// MFMA issue. Insert order per q-list unchanged -> bit-identical. Plus T5
// setprio around MFMA clusters (independent blocks/CU -> scheduler has
// role diversity to arbitrate).
__global__ __launch_bounds__(256, 2) void dist_topk_kernel(
    const unsigned short* __restrict__ xb, const float* __restrict__ sq,
    float* __restrict__ pscore) {
  const int t = threadIdx.x;
  const int wave = t >> 6, lane = t & 63;
  const int lrow = lane & 15, lquad = lane >> 4;
  const int rowBase = blockIdx.x * 256;
  const int chunk = blockIdx.y;
  const int j0 = chunk * CPC;
  const bool hasDiag = ((blockIdx.x >> 1) == (int)blockIdx.y);

  __shared__ unsigned short colsB[2][64 * DD];   // 2 x 16 KB, XOR-swizzled image
  __shared__ float sqs_all[CPC];                 // whole chunk's col bias, 2 KB

  // A fragments for 4 row-groups: lane holds X[row][k=lquad*8+j].
  const int r0 = rowBase + wave * 64 + lrow;     // group g row = r0 + g*16
  const unsigned short* ap0 = xb + (size_t)(r0)*DD + lquad * 8;
  const unsigned short* ap1 = xb + (size_t)(r0 + 16) * DD + lquad * 8;
  const unsigned short* ap2 = xb + (size_t)(r0 + 32) * DD + lquad * 8;
  const unsigned short* ap3 = xb + (size_t)(r0 + 48) * DD + lquad * 8;
  bf16x8 a00 = *(const bf16x8*)(ap0), a01 = *(const bf16x8*)(ap0 + 32),
         a02 = *(const bf16x8*)(ap0 + 64), a03 = *(const bf16x8*)(ap0 + 96);
  bf16x8 a10 = *(const bf16x8*)(ap1), a11 = *(const bf16x8*)(ap1 + 32),
         a12 = *(const bf16x8*)(ap1 + 64), a13 = *(const bf16x8*)(ap1 + 96);
  bf16x8 a20 = *(const bf16x8*)(ap2), a21 = *(const bf16x8*)(ap2 + 32),
         a22 = *(const bf16x8*)(ap2 + 64), a23 = *(const bf16x8*)(ap2 + 96);
  bf16x8 a30 = *(const bf16x8*)(ap3), a31 = *(const bf16x8*)(ap3 + 32),
         a32 = *(const bf16x8*)(ap3 + 64), a33 = *(const bf16x8*)(ap3 + 96);

  // Packed sorted lists (descending), one per row-group.
  float q00 = PACK_INIT, q01 = PACK_INIT, q02 = PACK_INIT, q03 = PACK_INIT,
        q04 = PACK_INIT;
  float q10 = PACK_INIT, q11 = PACK_INIT, q12 = PACK_INIT, q13 = PACK_INIT,
        q14 = PACK_INIT;
  float q20 = PACK_INIT, q21 = PACK_INIT, q22 = PACK_INIT, q23 = PACK_INIT,
        q24 = PACK_INIT;
  float q30 = PACK_INIT, q31 = PACK_INIT, q32 = PACK_INIT, q33 = PACK_INIT,
        q34 = PACK_INIT;

  // DMA source pre-swizzle: LDS[i] = src[p(i)] with the involution
  // p(i) = (i & ~15) | ((i&15) ^ ((i>>4)&15)); identical image to the old
  // reg-staged LDS[p(t)] = src[t] store (p is an involution, p(i+256k)=p(i)+256k).
  const int psl = (t & ~15) | ((t ^ (t >> 4)) & 15);

#define ISSUE_TILE(buf, jtrow)                                                 \
  {                                                                            \
    const float4* s_ = (const float4*)(xb + (size_t)(jtrow)*DD);               \
    char* l_ = (char*)(&colsB[buf][0]) + wave * 1024;                          \
    gload_lds16(s_ + psl, l_);                                                 \
    gload_lds16(s_ + psl + 256, l_ + 4096);                                    \
    gload_lds16(s_ + psl + 512, l_ + 8192);                                    \
    gload_lds16(s_ + psl + 768, l_ + 12288);                                   \
  }

  // b-frag reads for one ct (XOR-swizzled, verified layout).
#define BREAD(CT, B0, B1, B2, B3)                                              \
  {                                                                            \
    const unsigned short* bb_ = &colsB[cur][((CT)*16 + lrow) * DD];            \
    B0 = *(const bf16x8*)(bb_ + (((0 + lquad) ^ lrow) << 3));                  \
    B1 = *(const bf16x8*)(bb_ + (((4 + lquad) ^ lrow) << 3));                  \
    B2 = *(const bf16x8*)(bb_ + (((8 + lquad) ^ lrow) << 3));                  \
    B3 = *(const bf16x8*)(bb_ + (((12 + lquad) ^ lrow) << 3));                 \
  }

  // 16-MFMA cluster for one ct (identical op order to verified version).
#define MFMA16(B0, B1, B2, B3, AC0, AC1, AC2, AC3, NSQ)                        \
  __builtin_amdgcn_s_setprio(1);                                               \
  AC0 = __builtin_amdgcn_mfma_f32_16x16x32_bf16(B0, a00, NSQ, 0, 0, 0);        \
  AC1 = __builtin_amdgcn_mfma_f32_16x16x32_bf16(B0, a10, NSQ, 0, 0, 0);        \
  AC2 = __builtin_amdgcn_mfma_f32_16x16x32_bf16(B0, a20, NSQ, 0, 0, 0);        \
  AC3 = __builtin_amdgcn_mfma_f32_16x16x32_bf16(B0, a30, NSQ, 0, 0, 0);        \
  AC0 = __builtin_amdgcn_mfma_f32_16x16x32_bf16(B1, a01, AC0, 0, 0, 0);        \
  AC1 = __builtin_amdgcn_mfma_f32_16x16x32_bf16(B1, a11, AC1, 0, 0, 0);        \
  AC2 = __builtin_amdgcn_mfma_f32_16x16x32_bf16(B1, a21, AC2, 0, 0, 0);        \
  AC3 = __builtin_amdgcn_mfma_f32_16x16x32_bf16(B1, a31, AC3, 0, 0, 0);        \
  AC0 = __builtin_amdgcn_mfma_f32_16x16x32_bf16(B2, a02, AC0, 0, 0, 0);        \
  AC1 = __builtin_amdgcn_mfma_f32_16x16x32_bf16(B2, a12, AC1, 0, 0, 0);        \
  AC2 = __builtin_amdgcn_mfma_f32_16x16x32_bf16(B2, a22, AC2, 0, 0, 0);        \
  AC3 = __builtin_amdgcn_mfma_f32_16x16x32_bf16(B2, a32, AC3, 0, 0, 0);        \
  AC0 = __builtin_amdgcn_mfma_f32_16x16x32_bf16(B3, a03, AC0, 0, 0, 0);        \
  AC1 = __builtin_amdgcn_mfma_f32_16x16x32_bf16(B3, a13, AC1, 0, 0, 0);        \
  AC2 = __builtin_amdgcn_mfma_f32_16x16x32_bf16(B3, a23, AC2, 0, 0, 0);        \
  AC3 = __builtin_amdgcn_mfma_f32_16x16x32_bf16(B3, a33, AC3, 0, 0, 0);        \
  __builtin_amdgcn_s_setprio(0);

  // 16 packed inserts for one ct (same per-list order as verified version).
#define INS16(INSROW, AC0, AC1, AC2, AC3, COLB)                                \
  _Pragma("unroll")                                                            \
  for (int r = 0; r < 4; ++r) {                                                \
    const unsigned cr = (COLB) + r;                                            \
    INSROW(0, packsi(AC0[r], cr));                                             \
    INSROW(1, packsi(AC1[r], cr));                                             \
    INSROW(2, packsi(AC2[r], cr));                                             \
    INSROW(3, packsi(AC3[r], cr));                                             \
  }

  // Prologue: stage whole-chunk col bias + DMA tile 0.
  sqs_all[t] = sq[j0 + t];
  sqs_all[t + 256] = sq[j0 + 256 + t];
  ISSUE_TILE(0, j0)

  // Pipelined tile body: READS(ct+1); MFMA(ct+1); INSERTS(ct).
#define KBODY(INSROW)                                                          \
  for (int it = 0; it < TILES; ++it) {                                         \
    const int jt = j0 + it * 64;                                               \
    const int cur = it & 1;                                                    \
    __syncthreads(); /* drains this tile's DMA (vmcnt) + LDS writes */         \
    if (it + 1 < TILES) { ISSUE_TILE(cur ^ 1, jt + 64) }                       \
    const f32x4 nsq0 = *(const f32x4*)&sqs_all[it * 64 + 0 * 16 + lquad * 4];  \
    const f32x4 nsq1 = *(const f32x4*)&sqs_all[it * 64 + 1 * 16 + lquad * 4];  \
    const f32x4 nsq2 = *(const f32x4*)&sqs_all[it * 64 + 2 * 16 + lquad * 4];  \
    const f32x4 nsq3 = *(const f32x4*)&sqs_all[it * 64 + 3 * 16 + lquad * 4];  \
    bf16x8 bA0, bA1, bA2, bA3, bB0, bB1, bB2, bB3;                             \
    f32x4 acA0, acA1, acA2, acA3, acB0, acB1, acB2, acB3;                      \
    BREAD(0, bA0, bA1, bA2, bA3)                                               \
    BREAD(1, bB0, bB1, bB2, bB3)                                               \
    MFMA16(bA0, bA1, bA2, bA3, acA0, acA1, acA2, acA3, nsq0)                   \
    /* s0 */                                                                   \
    BREAD(2, bA0, bA1, bA2, bA3)                                               \
    MFMA16(bB0, bB1, bB2, bB3, acB0, acB1, acB2, acB3, nsq1)                   \
    INS16(INSROW, acA0, acA1, acA2, acA3, (unsigned)(jt + 0 * 16 + lquad * 4)) \
    /* s1 */                                                                   \
    BREAD(3, bB0, bB1, bB2, bB3)                                               \
    MFMA16(bA0, bA1, bA2, bA3, acA0, acA1, acA2, acA3, nsq2)                   \
    INS16(INSROW, acB0, acB1, acB2, acB3, (unsigned)(jt + 1 * 16 + lquad * 4)) \
    /* s2 */                                                                   \
    MFMA16(bB0, bB1, bB2, bB3, acB0, acB1, acB2, acB3, nsq3)                   \
    INS16(INSROW, acA0, acA1, acA2, acA3, (unsigned)(jt + 2 * 16 + lquad * 4)) \
    /* s3 */                                                                   \
    INS16(INSROW, acB0, acB1, acB2, acB3, (unsigned)(jt + 3 * 16 + lquad * 4)) \
  }

#define INS4(G, V) NET4(q##G##0, q##G##1, q##G##2, q##G##3, (V))
#define INS5(G, V) NET5(q##G##0, q##G##1, q##G##2, q##G##3, q##G##4, (V))

  if (hasDiag) {
    KBODY(INS5)
  } else {
    KBODY(INS4)
  }
#undef KBODY

  // Merge across lquads (lanes sharing lrow hold the same 4 rows).
#define MERGE4(G, M)                                                           \
  {                                                                            \
    float o0 = __shfl_xor(q##G##0, M), o1 = __shfl_xor(q##G##1, M),            \
          o2 = __shfl_xor(q##G##2, M), o3 = __shfl_xor(q##G##3, M);            \
    NET4(q##G##0, q##G##1, q##G##2, q##G##3, o0);                              \
    NET4(q##G##0, q##G##1, q##G##2, q##G##3, o1);                              \
    NET4(q##G##0, q##G##1, q##G##2, q##G##3, o2);                              \
    NET4(q##G##0, q##G##1, q##G##2, q##G##3, o3);                              \
  }
#define MERGE5(G, M)                                                           \
  {                                                                            \
    float o0 = __shfl_xor(q##G##0, M), o1 = __shfl_xor(q##G##1, M),            \
          o2 = __shfl_xor(q##G##2, M), o3 = __shfl_xor(q##G##3, M),            \
          o4 = __shfl_xor(q##G##4, M);                                         \
    NET5(q##G##0, q##G##1, q##G##2, q##G##3, q##G##4, o0);                     \
    NET5(q##G##0, q##G##1, q##G##2, q##G##3, q##G##4, o1);                     \
    NET5(q##G##0, q##G##1, q##G##2, q##G##3, q##G##4, o2);                     \
    NET5(q##G##0, q##G##1, q##G##2, q##G##3, q##G##4, o3);                     \
    NET5(q##G##0, q##G##1, q##G##2, q##G##3, q##G##4, o4);                     \
  }
  if (hasDiag) {
    MERGE5(0, 16) MERGE5(1, 16) MERGE5(2, 16) MERGE5(3, 16)
    MERGE5(0, 32) MERGE5(1, 32) MERGE5(2, 32) MERGE5(3, 32)
  } else {
    MERGE4(0, 16) MERGE4(1, 16) MERGE4(2, 16) MERGE4(3, 16)
    MERGE4(0, 32) MERGE4(1, 32) MERGE4(2, 32) MERGE4(3, 32)
  }

  if (lquad == 0) {
    // pscore layout: [row][CH*5] -> coalesced per-row read in final_kernel.
    float* b0p = pscore + (size_t)(r0)*80 + chunk * 5;
    b0p[0] = q00; b0p[1] = q01; b0p[2] = q02; b0p[3] = q03; b0p[4] = q04;
    float* b1p = pscore + (size_t)(r0 + 16) * 80 + chunk * 5;
    b1p[0] = q10; b1p[1] = q11; b1p[2] = q12; b1p[3] = q13; b1p[4] = q14;
    float* b2p = pscore + (size_t)(r0 + 32) * 80 + chunk * 5;
    b2p[0] = q20; b2p[1] = q21; b2p[2] = q22; b2p[3] = q23; b2p[4] = q24;
    float* b3p = pscore + (size_t)(r0 + 48) * 80 + chunk * 5;
    b3p[0] = q30; b3p[1] = q31; b3p[2] = q32; b3p[3] = q33; b3p[4] = q34;
  }
}

// Kernel 3: chunk merge (packed, max networks) -> neg idx -> exact fp32 hinge
// -> 64 bins. x[row]/pos[row] loads hoisted above the merge (independent).
__global__ __launch_bounds__(256) void final_kernel(const float* __restrict__ x,
                                                    const float* __restrict__ pos,
                                                    const float* __restrict__ pscore,
                                                    float* __restrict__ partial) {
  const int wave = threadIdx.x >> 6, lane = threadIdx.x & 63;
  const int row = blockIdx.x * 4 + wave;

  // Independent loads first: overlap with merge below.
  const float2 xv  = ((const float2*)(x   + (size_t)row  * DD))[lane];
  const float2 pv  = ((const float2*)(pos + (size_t)row  * DD))[lane];

  float q0 = PACK_INIT, q1 = PACK_INIT, q2 = PACK_INIT, q3 = PACK_INIT,
        q4 = PACK_INIT;
  if (lane < CH) {
    const float* b = pscore + (size_t)row * 80 + lane * 5;   // contiguous row
    q0 = b[0]; q1 = b[1]; q2 = b[2]; q3 = b[3]; q4 = b[4];
  }
#pragma unroll
  for (int m = 1; m < CH; m <<= 1) {
    float o0 = __shfl_xor(q0, m), o1 = __shfl_xor(q1, m), o2 = __shfl_xor(q2, m),
          o3 = __shfl_xor(q3, m), o4 = __shfl_xor(q4, m);
    NET5(q0, q1, q2, q3, q4, o0);
    NET5(q0, q1, q2, q3, q4, o1);
    NET5(q0, q1, q2, q3, q4, o2);
    NET5(q0, q1, q2, q3, q4, o3);
    NET5(q0, q1, q2, q3, q4, o4);
  }
  const int nidx = (int)(__float_as_uint(__shfl(q4, 0)) & 0x1FFFu);

  const float2 nvv = ((const float2*)(x + (size_t)nidx * DD))[lane];
  float a0 = xv.x - pv.x + 1e-6f, a1 = xv.y - pv.y + 1e-6f;
  float b0 = xv.x - nvv.x + 1e-6f, b1 = xv.y - nvv.y + 1e-6f;
  float dap = a0 * a0 + a1 * a1;
  float dan = b0 * b0 + b1 * b1;
#pragma unroll
  for (int off = 32; off; off >>= 1) {
    dap += __shfl_down(dap, off);
    dan += __shfl_down(dan, off);
  }
  __shared__ float hs[4];
  if (lane == 0) hs[wave] = fmaxf(sqrtf(dap) - sqrtf(dan) + 0.3f, 0.0f);
  __syncthreads();
  if (threadIdx.x == 0) {
    float s = hs[0] + hs[1] + hs[2] + hs[3];
    atomicAdd(&partial[blockIdx.x & (NPART - 1)], s);
  }
}

// Kernel 4: one wave sums the 64 bins -> mean.
__global__ __launch_bounds__(64) void reduce_kernel(const float* __restrict__ partial,
                                                    float* __restrict__ out) {
  float v = partial[threadIdx.x];
#pragma unroll
  for (int off = 32; off; off >>= 1) v += __shfl_down(v, off);
  if (threadIdx.x == 0) out[0] = v * (1.0f / 8192.0f);
}

extern "C" void kernel_launch(void* const* d_in, const int* in_sizes, int n_in,
                              void* d_out, int out_size, void* d_ws, size_t ws_size,
                              hipStream_t stream) {
  const float* x   = (const float*)d_in[0];
  const float* pos = (const float*)d_in[1];
  float* out = (float*)d_out;

  char* w = (char*)d_ws;
  unsigned short* xb = (unsigned short*)w;                       // 2 MB
  float* sq = (float*)(w + (size_t)NN * DD * 2);                 // 32 KB
  float* pscore = (float*)(w + (size_t)NN * DD * 2 + (size_t)NN * 4);  // 2.62 MB
  float* partial = (float*)(w + (size_t)NN * DD * 2 + (size_t)NN * 4 +
                            (size_t)NN * 80 * 4);                // 256 B

  prep_kernel<<<NN / 4, 256, 0, stream>>>(x, xb, sq, partial);
  dist_topk_kernel<<<dim3(NN / 256, CH), 256, 0, stream>>>(xb, sq, pscore);
  final_kernel<<<NN / 4, 256, 0, stream>>>(x, pos, pscore, partial);
  reduce_kernel<<<1, 64, 0, stream>>>(partial, out);
}